// Round 13
// baseline (180.604 us; speedup 1.0000x reference)
//
#include <hip/hip_runtime.h>
#include <math.h>

#define EPSF 1e-8f
#define WIN_LEN 256
#define HOP 128
#define NBINS 257          // rfft bins of 512
#define NUMBAND 15
#define NFRAMES 2499       // (320000-256)/128+1
#define NSTFT 2498         // NFRAMES-1
#define N_INTEL 30
#define NSEG 2469          // NSTFT - N_INTEL + 1
#define NB 32              // batch
#define T_LEN 320000
#define CLIP_VAL 5.623413251903491f   // 10^(15/20)
#define NHALF 2500         // half-frames (T_LEN/HOP)
#define AB_STRIDE 2560
#define NWX 1249           // k2 blocks in x (2 frames per block)

typedef float v2f __attribute__((ext_vector_type(2)));
typedef float v4f __attribute__((ext_vector_type(4)));

// ---- packed fp32 helpers (VOP3P; all operands are 64-bit VGPR pairs) ----
__device__ __forceinline__ void pk_fma_blo(v2f& d, v2f a, v2f b) {
    asm("v_pk_fma_f32 %0, %1, %2, %0 op_sel:[0,0,0] op_sel_hi:[1,0,1]"
        : "+v"(d) : "v"(a), "v"(b));
}
__device__ __forceinline__ void pk_fma_rot(v2f& d, v2f a, v2f b) {
    asm("v_pk_fma_f32 %0, %1, %2, %0 op_sel:[1,1,0] op_sel_hi:[0,1,1] neg_lo:[1,0,0]"
        : "+v"(d) : "v"(a), "v"(b));
}
__device__ __forceinline__ void pk_fma_s(v2f& d, v2f a, float s) {
    const v2f bv = { s, s };
    asm("v_pk_fma_f32 %0, %1, %2, %0"
        : "+v"(d) : "v"(a), "v"(bv));
}
__device__ __forceinline__ v2f pk_mul_s(v2f a, float s) {
    const v2f bv = { s, s };
    v2f d;
    asm("v_pk_mul_f32 %0, %1, %2" : "=v"(d) : "v"(a), "v"(bv));
    return d;
}
__device__ __forceinline__ v2f pk_add(v2f a, v2f b) {
    v2f d;
    asm("v_pk_add_f32 %0, %1, %2" : "=v"(d) : "v"(a), "v"(b));
    return d;
}
__device__ __forceinline__ v2f pk_sub(v2f a, v2f b) {
    v2f d;
    asm("v_pk_add_f32 %0, %1, %2 neg_lo:[0,1] neg_hi:[0,1]" : "=v"(d) : "v"(a), "v"(b));
    return d;
}
// (re,im)-packed: return B + (-i)*D = (B.re + D.im, B.im - D.re)
__device__ __forceinline__ v2f pk_bmi(v2f B, v2f D) {
    v2f d;
    asm("v_pk_add_f32 %0, %1, %2 op_sel:[1,0] op_sel_hi:[0,1] neg_hi:[1,0]"
        : "=v"(d) : "v"(D), "v"(B));
    return d;
}
// (re,im)-packed: return B + i*D = (B.re - D.im, B.im + D.re)
__device__ __forceinline__ v2f pk_bpi(v2f B, v2f D) {
    v2f d;
    asm("v_pk_add_f32 %0, %1, %2 op_sel:[1,0] op_sel_hi:[0,1] neg_lo:[1,0]"
        : "=v"(d) : "v"(D), "v"(B));
    return d;
}
__device__ __forceinline__ v2f pk_cmul(v2f a, v2f b) {
    v2f t;
    asm("v_pk_mul_f32 %0, %1, %2 op_sel:[0,0] op_sel_hi:[1,0]"
        : "=v"(t) : "v"(a), "v"(b));
    asm("v_pk_fma_f32 %0, %1, %2, %0 op_sel:[1,1,0] op_sel_hi:[0,1,1] neg_lo:[1,0,0]"
        : "+v"(t) : "v"(a), "v"(b));
    return t;
}
__device__ __forceinline__ void pk_rot(v2f& cs, v2f cksk) {
    v2f t;
    asm("v_pk_mul_f32 %0, %1, %2 op_sel:[0,0] op_sel_hi:[1,0]"
        : "=v"(t) : "v"(cs), "v"(cksk));
    asm("v_pk_fma_f32 %0, %0, %1, %2 op_sel:[1,1,0] op_sel_hi:[0,1,1] neg_lo:[1,0,0]"
        : "+v"(cs) : "v"(cksk), "v"(t));
}
__device__ __forceinline__ void pk_cfma(v2f& acc, v2f g, float wr, float wi) {
    const v2f wv = { wr, wi };
    pk_fma_blo(acc, g, wv);
    pk_fma_rot(acc, g, wv);
}
// pack two f32 -> f16x2 (single instr, RTZ)
__device__ __forceinline__ unsigned pk_f16(float a, float b) {
    unsigned u;
    asm("v_cvt_pkrtz_f16_f32 %0, %1, %2" : "=v"(u) : "v"(a), "v"(b));
    return u;
}
// unpack f16x2 -> (lo, hi) f32
__device__ __forceinline__ v2f unpk_f16(unsigned u) {
    float lo, hi;
    asm("v_cvt_f32_f16 %0, %1" : "=v"(lo) : "v"(u));
    asm("v_lshrrev_b32 %0, 16, %1\n\tv_cvt_f32_f16 %0, %0" : "=v"(hi) : "v"(u));
    return (v2f){ lo, hi };
}

// ---- workspace layout (bytes) ----
#define WS_COUNTS   0          // 32 int
#define WS_BANDLO   512        // 16 int
#define WS_BANDHI   768        // 16 int
#define WS_SRCFRM   5632       // 32*2499 int
#define WS_XTOB     325632     // ab scratch aliases (consumed before k2 writes)
#define WS_YTOB     5121792

// Per-half-frame windowed energy partials + (block 0,0 only) band scan and
// out zero-init.
__global__ __launch_bounds__(256)
void k1a_ab(const float* __restrict__ tgt, const float* __restrict__ win,
            const float* __restrict__ obm, float2* __restrict__ ab,
            int* __restrict__ band_lo, int* __restrict__ band_hi,
            float* __restrict__ out_)
{
    const int b = blockIdx.x;
    const int tid = threadIdx.x;
    const int h = blockIdx.y * 256 + tid;
    if (h < NHALF) {
        const float* xp = tgt + (size_t)b * T_LEN + (size_t)h * HOP;
        float sa = 0.f, sb = 0.f;
        #pragma unroll 4
        for (int u = 0; u < HOP; u += 4) {
            const float4 xv = *(const float4*)(xp + u);
            const float4 wl = *(const float4*)(win + u);
            const float4 wh = *(const float4*)(win + HOP + u);
            float a;
            a = xv.x * wl.x; sa = fmaf(a, a, sa);
            a = xv.y * wl.y; sa = fmaf(a, a, sa);
            a = xv.z * wl.z; sa = fmaf(a, a, sa);
            a = xv.w * wl.w; sa = fmaf(a, a, sa);
            a = xv.x * wh.x; sb = fmaf(a, a, sb);
            a = xv.y * wh.y; sb = fmaf(a, a, sb);
            a = xv.z * wh.z; sb = fmaf(a, a, sb);
            a = xv.w * wh.w; sb = fmaf(a, a, sb);
        }
        ab[(size_t)b * AB_STRIDE + h] = make_float2(sa, sb);
    }

    // ---- one-time init (block 0,0): band ranges, out zero
    if (b == 0 && blockIdx.y == 0) {
        if (tid < NUMBAND) {
            int lo = -1, hi = 0;
            for (int k = 0; k < NBINS; ++k) {
                if (obm[tid * NBINS + k] != 0.f) { if (lo < 0) lo = k; hi = k + 1; }
            }
            band_lo[tid] = (lo < 0) ? 0 : lo;
            band_hi[tid] = hi;
        }
        __syncthreads();
        if (tid == 0) {
            int lo = NBINS, hi = 0;
            for (int i = 0; i < NUMBAND; ++i) {
                if (band_lo[i] < lo) lo = band_lo[i];
                if (band_hi[i] > hi) hi = band_hi[i];
            }
            band_lo[NUMBAND] = lo;
            band_hi[NUMBAND] = hi;
        }
        if (tid < NB) out_[tid] = 0.f;
    }
}

__global__ __launch_bounds__(256)
void k1b_scan(const float2* __restrict__ ab,
              int* __restrict__ counts, int* __restrict__ srcfrm)
{
    const int b = blockIdx.x;
    const int tid = threadIdx.x;
    __shared__ float nr[NFRAMES];
    __shared__ float red[256];
    __shared__ int   sc[256];

    const float2* abp = ab + (size_t)b * AB_STRIDE;
    for (int f = tid; f < NFRAMES; f += 256) {
        const float2 p0 = abp[f];
        const float2 p1 = abp[f + 1];
        nr[f] = sqrtf(p0.x + p1.y);
    }
    __syncthreads();

    float mx = 0.f;
    for (int f = tid; f < NFRAMES; f += 256) mx = fmaxf(mx, nr[f]);
    red[tid] = mx;
    __syncthreads();
    for (int s = 128; s > 0; s >>= 1) {
        if (tid < s) red[tid] = fmaxf(red[tid], red[tid + s]);
        __syncthreads();
    }
    const float thr = (red[0] + EPSF) * 0.01f;   // 10^(-40/20)

    const int c0 = tid * 10;
    const int c1 = (c0 + 10 < NFRAMES) ? c0 + 10 : NFRAMES;
    int lc = 0;
    for (int f = c0; f < c1; ++f) if (nr[f] + EPSF > thr) ++lc;
    sc[tid] = lc;
    __syncthreads();
    #pragma unroll
    for (int off = 1; off < 256; off <<= 1) {
        int u = (tid >= off) ? sc[tid - off] : 0;
        __syncthreads();
        sc[tid] += u;
        __syncthreads();
    }
    if (tid == 0) counts[b] = sc[255];
    int pos = sc[tid] - lc;   // exclusive prefix
    int* sf = srcfrm + b * NFRAMES;
    for (int f = c0; f < c1; ++f) if (nr[f] + EPSF > thr) sf[pos++] = f;
}

// 128-thread block = 2 independent waves, each one STFT frame.
// z = x + i*y complex packing: ONE complex 512-pt DFT (256-sample support)
// yields both signals via Z[k] / Z[512-k] extraction at the band-sum stage.
// Stage 1 (radix-8 m-split): lane (m<4, c<16) computes
//   S'[c][m+4j] = W512^{(m+4j)c} * sum_{t1<16} z[16t1+c] W32^{(m+4j)t1}
//   (twiddle FOLDED here so stage 2 has no serial chain). f32 v2f in LDS.
// Stage 2: lane (m2<32, half): 16 independent ds_read_b64 + 16-pt radix-4
//   DFT; low half -> Z[m2+32p] p=0..6, hi half -> Z[m2+32p] p=9..15
//   (the conjugate-partner bins 512-k). Z stored f16x2 in dead frf buffer.
// NOTE: hi-half XOUT constants and the 448-k slot map assume base == 0
// (true for this obm: blo = 7).
__global__ __launch_bounds__(128)
void k2_stft_tob(const float* __restrict__ est, const float* __restrict__ tgt,
                 const float* __restrict__ win,
                 const int* __restrict__ counts, const int* __restrict__ srcfrm,
                 const int* __restrict__ band_lo, const int* __restrict__ band_hi,
                 float* __restrict__ xtob, float* __restrict__ ytob)
{
    // bijective XCD-chunked remap over NWX block-pairs
    const int lin = blockIdx.x;
    const int xcd = lin & 7, cidx = lin >> 3;
    const int q = NWX >> 3, r = NWX & 7;
    const int rl = (xcd < r ? xcd * (q + 1) : r * (q + 1) + (xcd - r) * q) + cidx;

    const int wave = threadIdx.x >> 6;
    const int tid = threadIdx.x & 63;   // lane in wave
    const int j = rl * 2 + wave;        // frame index, 0..2497

    const int b = blockIdx.y;
    const int cntb = counts[b];
    const bool valid = (j < cntb - 1);  // masked frames never consumed downstream

    __shared__ float frf[2][512];       // staging z=(x,y); Z (f16x2) alias later
    __shared__ v2f   sxr[2][16][34];    // S' per wave: [t0=c][m'] f32 (re,im)

    const int* sf = srcfrm + b * NFRAMES;
    const float* xg = tgt + (size_t)b * T_LEN;
    const float* yg = est + (size_t)b * T_LEN;

    // ---- staging: lane builds samples 4tid..4tid+3 (branch wave-uniform)
    {
        const int t4 = 4 * tid;
        v4f xv = { 0.f, 0.f, 0.f, 0.f }, yv = xv;
        const v4f wa = *(const v4f*)&win[t4];
        if (valid) {
            const int k0 = sf[j];
            if (tid < 32) {                   // t < HOP
                xv = *(const v4f*)&xg[k0 * HOP + t4] * wa;
                yv = *(const v4f*)&yg[k0 * HOP + t4] * wa;
                if (j >= 1) {
                    const int km = sf[j - 1];
                    const v4f wb = *(const v4f*)&win[HOP + t4];
                    xv += *(const v4f*)&xg[km * HOP + HOP + t4] * wb;
                    yv += *(const v4f*)&yg[km * HOP + HOP + t4] * wb;
                }
            } else {                          // t >= HOP
                const int kp = sf[j + 1];
                const v4f wb = *(const v4f*)&win[t4 - HOP];
                xv = *(const v4f*)&xg[k0 * HOP + t4] * wa
                   + *(const v4f*)&xg[kp * HOP + t4 - HOP] * wb;
                yv = *(const v4f*)&yg[k0 * HOP + t4] * wa
                   + *(const v4f*)&yg[kp * HOP + t4 - HOP] * wb;
            }
        }
        xv *= wa; yv *= wa;
        const v4f lo = { xv.x, yv.x, xv.y, yv.y };
        const v4f hi = { xv.z, yv.z, xv.w, yv.w };
        *(v4f*)&frf[wave][2 * t4]     = lo;
        *(v4f*)&frf[wave][2 * t4 + 4] = hi;
    }
    __syncthreads();

    // ---- Stage 1: complex radix-8 m-split + twiddle fold
    {
        const int m = tid & 3;
        const int c = tid >> 2;            // column t0 = c, 0..15
        const float ke = (m == 0) ? 1.f : (m == 2) ? -1.f : 0.f;
        const float ki = (m == 1) ? -1.f : (m == 3) ? 1.f : 0.f;  // (-i)^m = ke + i ki
        const float angm = -0.19634954084936207f * (float)m;      // -2pi m/32
        const v2f cksk = { __cosf(angm), __sinf(angm) };
        const v2f zv = { 0.f, 0.f };
        v2f cs = { 1.f, 0.f };
        v2f U[8];
        #pragma unroll
        for (int rr = 0; rr < 8; ++rr) {
            const v2f za = *(const v2f*)&frf[wave][2 * (16 * rr + c)];
            const v2f zb = *(const v2f*)&frf[wave][2 * (16 * rr + 128 + c)];
            const v2f tb = pk_bmi(zv, zb);        // (-i) * zb
            v2f pre = za;
            pk_fma_s(pre, zb, ke);
            pk_fma_s(pre, tb, -ki);               // pre = za + (ke + i ki) * zb
            U[rr] = pk_cmul(cs, pre);
            pk_rot(cs, cksk);
        }
        // 8-pt DIF FFT over rr (complex, (re,im)-packed)
        const float C2 = 0.70710678118654752f;
        v2f A[8];
        A[0] = pk_add(U[0], U[4]); A[1] = pk_add(U[1], U[5]);
        A[2] = pk_add(U[2], U[6]); A[3] = pk_add(U[3], U[7]);
        {
            v2f d;
            d = pk_sub(U[0], U[4]); A[4] = d;
            d = pk_sub(U[1], U[5]); A[5] = pk_mul_s(pk_bmi(d, d), C2);
            d = pk_sub(U[2], U[6]); A[6] = pk_bmi(zv, d);
            d = pk_sub(U[3], U[7]); A[7] = pk_mul_s(pk_bmi(zv, pk_bmi(d, d)), C2);
        }
        v2f Bv[8];
        #pragma unroll
        for (int g = 0; g < 8; g += 4) {
            Bv[g + 0] = pk_add(A[g + 0], A[g + 2]);
            Bv[g + 1] = pk_add(A[g + 1], A[g + 3]);
            Bv[g + 2] = pk_sub(A[g + 0], A[g + 2]);
            Bv[g + 3] = pk_bmi(zv, pk_sub(A[g + 1], A[g + 3]));   // -i * (A1-A3)
        }
        // fold stage-2 twiddle: tw[j] = W512^{(m+4j)c}
        const float a0  = -0.012271846303085130f * (float)(m * c);  // -2pi mc/512
        const float asr = -0.049087385212340517f * (float)c;        // -2pi 4c/512
        v2f bt = { __cosf(a0), __sinf(a0) };
        const v2f stp = { __cosf(asr), __sinf(asr) };
        v2f twj[8];
        #pragma unroll
        for (int jj = 0; jj < 8; ++jj) { twj[jj] = bt; pk_rot(bt, stp); }
        const int kmap[8] = { 0, 4, 2, 6, 1, 5, 3, 7 };   // DIF bitrev3
        #pragma unroll
        for (int p = 0; p < 8; ++p) {
            const int pb = p & ~1;
            const v2f o = (p & 1) ? pk_sub(Bv[pb], Bv[pb + 1])
                                  : pk_add(Bv[pb], Bv[pb + 1]);
            const int jj = kmap[p];
            sxr[wave][c][m + 4 * jj] = pk_cmul(twj[jj], o);
        }
    }
    __syncthreads();

    // ---- Stage 2: lane (m2, half) -> 7 Z bins via pure 16-pt radix-4 DFT
    const int blo = band_lo[NUMBAND];
    const int base = blo & ~31;          // == 0 for this obm
    unsigned* zOut = (unsigned*)&frf[wave][0];
    {
        const int m2 = tid & 31;
        const int half = tid >> 5;
        v2f V[16];
        #pragma unroll
        for (int t0 = 0; t0 < 16; ++t0) V[t0] = sxr[wave][t0][m2];
        v2f G[4][4];
        #pragma unroll
        for (int rr = 0; rr < 4; ++rr) {
            const v2f A = pk_add(V[rr], V[rr + 8]);
            const v2f B = pk_sub(V[rr], V[rr + 8]);
            const v2f C = pk_add(V[rr + 4], V[rr + 12]);
            const v2f D = pk_sub(V[rr + 4], V[rr + 12]);
            G[0][rr] = pk_add(A, C);
            G[2][rr] = pk_sub(A, C);
            G[1][rr] = pk_bmi(B, D);
            G[3][rr] = pk_bpi(B, D);
        }
        #define C1 0.92387953251f
        #define S1 0.38268343236f
        #define C2c 0.70710678119f
        #define XOUTZ(SLOT, D, W1R, W1I, W2R, W2I, W3R, W3I) { \
            v2f a_ = G[D][0]; \
            pk_cfma(a_, G[D][1], W1R, W1I); \
            pk_cfma(a_, G[D][2], W2R, W2I); \
            pk_cfma(a_, G[D][3], W3R, W3I); \
            zOut[SLOT] = pk_f16(a_.x, a_.y); }
        if (half == 0) {
            { const v2f a_ = pk_add(pk_add(G[0][0], G[0][1]), pk_add(G[0][2], G[0][3]));
              zOut[m2] = pk_f16(a_.x, a_.y); }
            XOUTZ(m2 + 32, 1,  C1, -S1,     C2c, -C2c,   S1, -C1)
            XOUTZ(m2 + 64, 2,  C2c, -C2c,   0.f, -1.f,  -C2c, -C2c)
            XOUTZ(m2 + 96, 3,  S1, -C1,    -C2c, -C2c,  -C1,  S1)
            { const v2f t1_ = pk_sub(G[0][0], G[0][2]);
              const v2f t2_ = pk_sub(G[0][1], G[0][3]);
              const v2f a_ = pk_bmi(t1_, t2_);
              zOut[m2 + 128] = pk_f16(a_.x, a_.y); }
            XOUTZ(m2 + 160, 1, -S1, -C1,    -C2c,  C2c,   C1,  S1)
            XOUTZ(m2 + 192, 2, -C2c, -C2c,   0.f,  1.f,   C2c, -C2c)
        } else {
            // p = 9..15 (bins 288..511 = conjugate partners 512-k)
            XOUTZ(224 + m2,       1, -C1,  S1,    C2c, -C2c,  -S1,  C1)
            XOUTZ(224 + m2 + 32,  2, -C2c,  C2c,  0.f, -1.f,   C2c,  C2c)
            XOUTZ(224 + m2 + 64,  3, -S1,  C1,   -C2c, -C2c,   C1, -S1)
            { const v2f t1_ = pk_sub(G[0][0], G[0][2]);
              const v2f t2_ = pk_sub(G[0][1], G[0][3]);
              const v2f a_ = pk_bpi(t1_, t2_);                 // W16^12 = +i
              zOut[224 + m2 + 96] = pk_f16(a_.x, a_.y); }
            XOUTZ(224 + m2 + 128, 1,  S1,  C1,   -C2c,  C2c,  -C1, -S1)
            XOUTZ(224 + m2 + 160, 2,  C2c,  C2c,  0.f,  1.f,  -C2c,  C2c)
            XOUTZ(224 + m2 + 192, 3,  C1,  S1,    C2c,  C2c,   S1,  C1)
        }
        #undef XOUTZ
    }
    __syncthreads();

    // ---- band sums with Z / Z-conj extraction: 4 lanes per band
    if (tid < 4 * NUMBAND && valid) {
        const int band = tid >> 2, s = tid & 3;
        const int lo = band_lo[band], hi = band_hi[band];
        float sx = 0.f, sy = 0.f;
        for (int k = lo + s; k < hi; k += 4) {
            const int kk = k - base;
            const v2f zk = unpk_f16(zOut[kk]);          // Z[k]
            const v2f zr = unpk_f16(zOut[448 - kk]);    // Z[512-k]
            const float e1 = zk.x + zr.x, e2 = zk.y - zr.y;   // 2X
            const float e3 = zk.y + zr.y, e4 = zk.x - zr.x;   // 2Y
            sx = fmaf(e1, e1, sx); sx = fmaf(e2, e2, sx);
            sy = fmaf(e3, e3, sy); sy = fmaf(e4, e4, sy);
        }
        sx += __shfl_xor(sx, 1, 64);  sx += __shfl_xor(sx, 2, 64);
        sy += __shfl_xor(sy, 1, 64);  sy += __shfl_xor(sy, 2, 64);
        if (s == 0) {
            xtob[((size_t)b * NUMBAND + band) * NSTFT + j] = sqrtf(0.25f * sx + EPSF);
            ytob[((size_t)b * NUMBAND + band) * NSTFT + j] = sqrtf(0.25f * sy + EPSF);
        }
    }
}

__global__ __launch_bounds__(256)
void k3_corr(const float* __restrict__ xtob, const float* __restrict__ ytob,
             const int* __restrict__ counts, float* __restrict__ out_)
{
    const int bb = blockIdx.y;
    const int b = bb / NUMBAND;
    const int band = bb % NUMBAND;
    const int s_base = blockIdx.x * 256;
    const int tid = threadIdx.x;
    const int seg = s_base + tid;

    __shared__ v2f lxy[256 + N_INTEL - 1];
    const float* xr = xtob + ((size_t)b * NUMBAND + band) * NSTFT;
    const float* yr = ytob + ((size_t)b * NUMBAND + band) * NSTFT;
    for (int i = tid; i < 256 + N_INTEL - 1; i += 256) {
        const int g = s_base + i;
        v2f v = { 0.f, 0.f };
        if (g < NSTFT) v = (v2f){ xr[g], yr[g] };
        lxy[i] = v;
    }
    __syncthreads();

    int nvalid = counts[b] - N_INTEL;
    if (nvalid < 0) nvalid = 0;
    if (nvalid > NSEG) nvalid = NSEG;

    float d = 0.f;
    if (seg < nvalid) {
        float xv[N_INTEL], yv[N_INTEL];
        float sx2 = 0.f, sy2 = 0.f;
        #pragma unroll
        for (int i = 0; i < N_INTEL; ++i) {
            const v2f v = lxy[tid + i];
            xv[i] = v.x; yv[i] = v.y;
            sx2 = fmaf(xv[i], xv[i], sx2);
            sy2 = fmaf(yv[i], yv[i], sy2);
        }
        const float nc = sqrtf(sx2) / (sqrtf(sy2) + EPSF);
        float sy = 0.f, sx = 0.f;
        #pragma unroll
        for (int i = 0; i < N_INTEL; ++i) {
            const float yp = fminf(yv[i] * nc, xv[i] * (1.f + CLIP_VAL));
            yv[i] = yp;
            sy += yp; sx += xv[i];
        }
        const float my = sy * (1.f / N_INTEL);
        const float mxm = sx * (1.f / N_INTEL);
        float num = 0.f, dy = 0.f, dx2 = 0.f;
        #pragma unroll
        for (int i = 0; i < N_INTEL; ++i) {
            const float a = yv[i] - my;
            const float c = xv[i] - mxm;
            num = fmaf(a, c, num);
            dy  = fmaf(a, a, dy);
            dx2 = fmaf(c, c, dx2);
        }
        d = num / ((sqrtf(dy) + EPSF) * (sqrtf(dx2) + EPSF));
    }

    #pragma unroll
    for (int o = 32; o > 0; o >>= 1) d += __shfl_down(d, o, 64);
    __shared__ float wsum[4];
    const int lane = threadIdx.x & 63, wid = threadIdx.x >> 6;
    if (lane == 0) wsum[wid] = d;
    __syncthreads();
    if (threadIdx.x == 0) {
        const float scale = -1.f / ((float)NUMBAND * ((float)nvalid + EPSF));
        atomicAdd(&out_[b], (wsum[0] + wsum[1] + wsum[2] + wsum[3]) * scale);
    }
}

extern "C" void kernel_launch(void* const* d_in, const int* in_sizes, int n_in,
                              void* d_out, int out_size, void* d_ws, size_t ws_size,
                              hipStream_t stream) {
    (void)in_sizes; (void)n_in; (void)out_size; (void)ws_size;
    const float* est = (const float*)d_in[0];
    const float* tgt = (const float*)d_in[1];
    const float* win = (const float*)d_in[2];
    const float* obm = (const float*)d_in[3];
    float* out = (float*)d_out;

    char* ws = (char*)d_ws;
    int*   counts  = (int*)(ws + WS_COUNTS);
    int*   band_lo = (int*)(ws + WS_BANDLO);
    int*   band_hi = (int*)(ws + WS_BANDHI);
    int*   srcfrm  = (int*)(ws + WS_SRCFRM);
    float* xtob    = (float*)(ws + WS_XTOB);
    float* ytob    = (float*)(ws + WS_YTOB);
    float2* ab     = (float2*)xtob;  // scratch alias: consumed by k1b before k2 writes

    k1a_ab<<<dim3(NB, 10), dim3(256), 0, stream>>>(tgt, win, obm, ab,
                                                   band_lo, band_hi, out);
    k1b_scan<<<dim3(NB), dim3(256), 0, stream>>>(ab, counts, srcfrm);
    k2_stft_tob<<<dim3(NWX, NB), dim3(128), 0, stream>>>(est, tgt, win, counts, srcfrm,
                                                         band_lo, band_hi, xtob, ytob);
    k3_corr<<<dim3((NSEG + 255) / 256, NB * NUMBAND), dim3(256), 0, stream>>>(xtob, ytob,
                                                                              counts, out);
}

// Round 14
// 172.414 us; speedup vs baseline: 1.0475x; 1.0475x over previous
//
#include <hip/hip_runtime.h>
#include <math.h>

#define EPSF 1e-8f
#define WIN_LEN 256
#define HOP 128
#define NBINS 257          // rfft bins of 512
#define NUMBAND 15
#define NFRAMES 2499       // (320000-256)/128+1
#define NSTFT 2498         // NFRAMES-1
#define N_INTEL 30
#define NSEG 2469          // NSTFT - N_INTEL + 1
#define NB 32              // batch
#define T_LEN 320000
#define CLIP_VAL 5.623413251903491f   // 10^(15/20)
#define NHALF 2500         // half-frames (T_LEN/HOP)
#define AB_STRIDE 2560
#define NWX 1249           // k2 blocks in x (2 frames per block)

typedef float v2f __attribute__((ext_vector_type(2)));
typedef float v4f __attribute__((ext_vector_type(4)));

// ---- packed fp32 helpers (VOP3P; all operands are 64-bit VGPR pairs) ----
__device__ __forceinline__ void pk_fma_blo(v2f& d, v2f a, v2f b) {
    asm("v_pk_fma_f32 %0, %1, %2, %0 op_sel:[0,0,0] op_sel_hi:[1,0,1]"
        : "+v"(d) : "v"(a), "v"(b));
}
__device__ __forceinline__ void pk_fma_rot(v2f& d, v2f a, v2f b) {
    asm("v_pk_fma_f32 %0, %1, %2, %0 op_sel:[1,1,0] op_sel_hi:[0,1,1] neg_lo:[1,0,0]"
        : "+v"(d) : "v"(a), "v"(b));
}
__device__ __forceinline__ void pk_fma_nbhi(v2f& d, v2f a, v2f b) {
    asm("v_pk_fma_f32 %0, %1, %2, %0 op_sel:[0,1,0] op_sel_hi:[1,1,1] neg_lo:[1,0,0] neg_hi:[1,0,0]"
        : "+v"(d) : "v"(a), "v"(b));
}
__device__ __forceinline__ void pk_fma_s(v2f& d, v2f a, float s) {
    const v2f bv = { s, s };
    asm("v_pk_fma_f32 %0, %1, %2, %0"
        : "+v"(d) : "v"(a), "v"(bv));
}
__device__ __forceinline__ v2f pk_mul_blo(v2f a, v2f b) {
    v2f d;
    asm("v_pk_mul_f32 %0, %1, %2 op_sel:[0,0] op_sel_hi:[1,0]"
        : "=v"(d) : "v"(a), "v"(b));
    return d;
}
__device__ __forceinline__ v2f pk_mul_bhi(v2f a, v2f b) {
    v2f d;
    asm("v_pk_mul_f32 %0, %1, %2 op_sel:[0,1] op_sel_hi:[1,1]"
        : "=v"(d) : "v"(a), "v"(b));
    return d;
}
__device__ __forceinline__ v2f pk_mul_s(v2f a, float s) {
    const v2f bv = { s, s };
    v2f d;
    asm("v_pk_mul_f32 %0, %1, %2" : "=v"(d) : "v"(a), "v"(bv));
    return d;
}
__device__ __forceinline__ v2f pk_add(v2f a, v2f b) {
    v2f d;
    asm("v_pk_add_f32 %0, %1, %2" : "=v"(d) : "v"(a), "v"(b));
    return d;
}
__device__ __forceinline__ v2f pk_sub(v2f a, v2f b) {
    v2f d;
    asm("v_pk_add_f32 %0, %1, %2 neg_lo:[0,1] neg_hi:[0,1]" : "=v"(d) : "v"(a), "v"(b));
    return d;
}
// (re,im)-packed: return B + (-i)*D
__device__ __forceinline__ v2f pk_bmi(v2f B, v2f D) {
    v2f d;
    asm("v_pk_add_f32 %0, %1, %2 op_sel:[1,0] op_sel_hi:[0,1] neg_hi:[1,0]"
        : "=v"(d) : "v"(D), "v"(B));
    return d;
}
// (re,im)-packed: return B + i*D
__device__ __forceinline__ v2f pk_bpi(v2f B, v2f D) {
    v2f d;
    asm("v_pk_add_f32 %0, %1, %2 op_sel:[1,0] op_sel_hi:[0,1] neg_lo:[1,0]"
        : "=v"(d) : "v"(D), "v"(B));
    return d;
}
__device__ __forceinline__ v2f pk_cmul(v2f a, v2f b) {
    v2f t;
    asm("v_pk_mul_f32 %0, %1, %2 op_sel:[0,0] op_sel_hi:[1,0]"
        : "=v"(t) : "v"(a), "v"(b));
    asm("v_pk_fma_f32 %0, %1, %2, %0 op_sel:[1,1,0] op_sel_hi:[0,1,1] neg_lo:[1,0,0]"
        : "+v"(t) : "v"(a), "v"(b));
    return t;
}
__device__ __forceinline__ void pk_rot(v2f& cs, v2f cksk) {
    v2f t;
    asm("v_pk_mul_f32 %0, %1, %2 op_sel:[0,0] op_sel_hi:[1,0]"
        : "=v"(t) : "v"(cs), "v"(cksk));
    asm("v_pk_fma_f32 %0, %0, %1, %2 op_sel:[1,1,0] op_sel_hi:[0,1,1] neg_lo:[1,0,0]"
        : "+v"(cs) : "v"(cksk), "v"(t));
}
__device__ __forceinline__ void pk_cfma(v2f& acc, v2f g, float wr, float wi) {
    const v2f wv = { wr, wi };
    pk_fma_blo(acc, g, wv);
    pk_fma_rot(acc, g, wv);
}
// pack two f32 -> f16x2 (single instr, RTZ)
__device__ __forceinline__ unsigned pk_f16(float a, float b) {
    unsigned u;
    asm("v_cvt_pkrtz_f16_f32 %0, %1, %2" : "=v"(u) : "v"(a), "v"(b));
    return u;
}
// unpack f16x2 -> (lo, hi) f32
__device__ __forceinline__ v2f unpk_f16(unsigned u) {
    float lo, hi;
    asm("v_cvt_f32_f16 %0, %1" : "=v"(lo) : "v"(u));
    asm("v_lshrrev_b32 %0, 16, %1\n\tv_cvt_f32_f16 %0, %0" : "=v"(hi) : "v"(u));
    return (v2f){ lo, hi };
}

// ---- workspace layout (bytes) ----
#define WS_COUNTS   0          // 32 int
#define WS_BANDLO   512        // 16 int
#define WS_BANDHI   768        // 16 int
#define WS_SRCFRM   5632       // 32*2499 int
#define WS_XTOB     325632     // ab scratch aliases (consumed before k2 writes)
#define WS_YTOB     5121792

// Per-half-frame windowed energy partials + (block 0,0 only) band scan and
// out zero-init.
__global__ __launch_bounds__(256)
void k1a_ab(const float* __restrict__ tgt, const float* __restrict__ win,
            const float* __restrict__ obm, float2* __restrict__ ab,
            int* __restrict__ band_lo, int* __restrict__ band_hi,
            float* __restrict__ out_)
{
    const int b = blockIdx.x;
    const int tid = threadIdx.x;
    const int h = blockIdx.y * 256 + tid;
    if (h < NHALF) {
        const float* xp = tgt + (size_t)b * T_LEN + (size_t)h * HOP;
        float sa = 0.f, sb = 0.f;
        #pragma unroll 4
        for (int u = 0; u < HOP; u += 4) {
            const float4 xv = *(const float4*)(xp + u);
            const float4 wl = *(const float4*)(win + u);
            const float4 wh = *(const float4*)(win + HOP + u);
            float a;
            a = xv.x * wl.x; sa = fmaf(a, a, sa);
            a = xv.y * wl.y; sa = fmaf(a, a, sa);
            a = xv.z * wl.z; sa = fmaf(a, a, sa);
            a = xv.w * wl.w; sa = fmaf(a, a, sa);
            a = xv.x * wh.x; sb = fmaf(a, a, sb);
            a = xv.y * wh.y; sb = fmaf(a, a, sb);
            a = xv.z * wh.z; sb = fmaf(a, a, sb);
            a = xv.w * wh.w; sb = fmaf(a, a, sb);
        }
        ab[(size_t)b * AB_STRIDE + h] = make_float2(sa, sb);
    }

    // ---- one-time init (block 0,0): band ranges, out zero
    if (b == 0 && blockIdx.y == 0) {
        if (tid < NUMBAND) {
            int lo = -1, hi = 0;
            for (int k = 0; k < NBINS; ++k) {
                if (obm[tid * NBINS + k] != 0.f) { if (lo < 0) lo = k; hi = k + 1; }
            }
            band_lo[tid] = (lo < 0) ? 0 : lo;
            band_hi[tid] = hi;
        }
        __syncthreads();
        if (tid == 0) {
            int lo = NBINS, hi = 0;
            for (int i = 0; i < NUMBAND; ++i) {
                if (band_lo[i] < lo) lo = band_lo[i];
                if (band_hi[i] > hi) hi = band_hi[i];
            }
            band_lo[NUMBAND] = lo;
            band_hi[NUMBAND] = hi;
        }
        if (tid < NB) out_[tid] = 0.f;
    }
}

// VAD scan: wave-level reductions (shfl), 4 barriers total.
__global__ __launch_bounds__(256)
void k1b_scan(const float2* __restrict__ ab,
              int* __restrict__ counts, int* __restrict__ srcfrm)
{
    const int b = blockIdx.x;
    const int tid = threadIdx.x;
    const int lane = tid & 63, wid = tid >> 6;
    __shared__ float nr[NFRAMES];
    __shared__ float wmax[4];
    __shared__ int   wtot[4];
    __shared__ int   woff[4];

    const float2* abp = ab + (size_t)b * AB_STRIDE;
    for (int f = tid; f < NFRAMES; f += 256) {
        const float2 p0 = abp[f];
        const float2 p1 = abp[f + 1];
        nr[f] = sqrtf(p0.x + p1.y);
    }
    __syncthreads();

    float mx = 0.f;
    for (int f = tid; f < NFRAMES; f += 256) mx = fmaxf(mx, nr[f]);
    #pragma unroll
    for (int o = 32; o > 0; o >>= 1) mx = fmaxf(mx, __shfl_xor(mx, o, 64));
    if (lane == 0) wmax[wid] = mx;
    __syncthreads();
    const float thr = (fmaxf(fmaxf(wmax[0], wmax[1]), fmaxf(wmax[2], wmax[3]))
                       + EPSF) * 0.01f;   // 10^(-40/20)

    const int c0 = tid * 10;
    const int c1 = (c0 + 10 < NFRAMES) ? c0 + 10 : NFRAMES;
    int lc = 0;
    for (int f = c0; f < c1; ++f) if (nr[f] + EPSF > thr) ++lc;
    // wave-inclusive scan over per-thread counts
    int v = lc;
    #pragma unroll
    for (int off = 1; off < 64; off <<= 1) {
        const int u = __shfl_up(v, off, 64);
        if (lane >= off) v += u;
    }
    if (lane == 63) wtot[wid] = v;
    __syncthreads();
    if (tid == 0) {
        int run = 0;
        #pragma unroll
        for (int i = 0; i < 4; ++i) { woff[i] = run; run += wtot[i]; }
        counts[b] = run;
    }
    __syncthreads();
    int pos = woff[wid] + v - lc;   // exclusive prefix
    int* sf = srcfrm + b * NFRAMES;
    for (int f = c0; f < c1; ++f) if (nr[f] + EPSF > thr) sf[pos++] = f;
}

// 128-thread block = 2 independent waves, each one STFT frame.
// Per wave: two-stage DFT (512 = 32 x 16), in-register twiddle chains, packed
// VOP3P butterflies, stage-1 output S stored as f16x2 in LDS ([t0][m2] u32,
// row stride 34 — bank-audited: writes 2-way (free), reads conflict-free).
__global__ __launch_bounds__(128)
void k2_stft_tob(const float* __restrict__ est, const float* __restrict__ tgt,
                 const float* __restrict__ win,
                 const int* __restrict__ counts, const int* __restrict__ srcfrm,
                 const int* __restrict__ band_lo, const int* __restrict__ band_hi,
                 float* __restrict__ xtob, float* __restrict__ ytob)
{
    // bijective XCD-chunked remap over NWX block-pairs
    const int lin = blockIdx.x;
    const int xcd = lin & 7, cidx = lin >> 3;
    const int q = NWX >> 3, r = NWX & 7;
    const int rl = (xcd < r ? xcd * (q + 1) : r * (q + 1) + (xcd - r) * q) + cidx;

    const int wave = threadIdx.x >> 6;
    const int tid = threadIdx.x & 63;   // lane in wave
    const int j = rl * 2 + wave;        // frame index, 0..2497

    const int b = blockIdx.y;
    const int cntb = counts[b];
    const bool valid = (j < cntb - 1);  // masked frames never consumed downstream

    __shared__ float    frf[2][512];          // staging; px/py alias later
    __shared__ unsigned sxh[2][2][16][34];    // [wave][sig][t0][m2] f16x2

    const int* sf = srcfrm + b * NFRAMES;
    const float* xg = tgt + (size_t)b * T_LEN;
    const float* yg = est + (size_t)b * T_LEN;

    // ---- staging: lane builds samples 4tid..4tid+3 (branch wave-uniform)
    {
        const int t4 = 4 * tid;
        v4f xv = { 0.f, 0.f, 0.f, 0.f }, yv = xv;
        const v4f wa = *(const v4f*)&win[t4];
        if (valid) {
            const int k0 = sf[j];
            if (tid < 32) {                   // t < HOP
                xv = *(const v4f*)&xg[k0 * HOP + t4] * wa;
                yv = *(const v4f*)&yg[k0 * HOP + t4] * wa;
                if (j >= 1) {
                    const int km = sf[j - 1];
                    const v4f wb = *(const v4f*)&win[HOP + t4];
                    xv += *(const v4f*)&xg[km * HOP + HOP + t4] * wb;
                    yv += *(const v4f*)&yg[km * HOP + HOP + t4] * wb;
                }
            } else {                          // t >= HOP
                const int kp = sf[j + 1];
                const v4f wb = *(const v4f*)&win[t4 - HOP];
                xv = *(const v4f*)&xg[k0 * HOP + t4] * wa
                   + *(const v4f*)&xg[kp * HOP + t4 - HOP] * wb;
                yv = *(const v4f*)&yg[k0 * HOP + t4] * wa
                   + *(const v4f*)&yg[kp * HOP + t4 - HOP] * wb;
            }
        }
        xv *= wa; yv *= wa;
        const v4f lo = { xv.x, yv.x, xv.y, yv.y };
        const v4f hi = { xv.z, yv.z, xv.w, yv.w };
        *(v4f*)&frf[wave][2 * t4]     = lo;
        *(v4f*)&frf[wave][2 * t4 + 4] = hi;
    }
    __syncthreads();

    // ---- Stage 1: radix-8 m-split, chain twiddles, packed butterflies
    {
        const int m = tid & 3;
        const int c = tid >> 2;            // 0..15
        const float ke = (m == 0) ? 1.f : (m == 2) ? -1.f : 0.f;
        const float ki = (m == 1) ? -1.f : (m == 3) ? 1.f : 0.f;
        const float ang = -0.19634954084936207f * (float)m;  // -2pi m/32
        const v2f cksk = { __cosf(ang), __sinf(ang) };
        v2f cs = { 1.f, 0.f };
        v2f URe[8], UIm[8];
        #pragma unroll
        for (int rr = 0; rr < 8; ++rr) {
            const v2f za = *(const v2f*)&frf[wave][2 * (16 * rr + c)];
            const v2f zb = *(const v2f*)&frf[wave][2 * (16 * rr + 128 + c)];
            v2f pre_re = za; pk_fma_s(pre_re, zb, ke);
            const v2f pre_im = pk_mul_s(zb, ki);
            v2f ur = pk_mul_blo(pre_re, cs); pk_fma_nbhi(ur, pre_im, cs);
            v2f ui = pk_mul_bhi(pre_re, cs); pk_fma_blo(ui, pre_im, cs);
            URe[rr] = ur; UIm[rr] = ui;
            pk_rot(cs, cksk);
        }
        // 8-pt DIF FFT over r (complex; each v2f packs both signals)
        v2f ARe[8], AIm[8];
        {
            const float C2 = 0.70710678118654752f;
            v2f dR, dI;
            #pragma unroll
            for (int rr = 0; rr < 4; ++rr) {
                ARe[rr] = pk_add(URe[rr], URe[rr + 4]);
                AIm[rr] = pk_add(UIm[rr], UIm[rr + 4]);
            }
            ARe[4] = pk_sub(URe[0], URe[4]);     AIm[4] = pk_sub(UIm[0], UIm[4]);
            dR = pk_sub(URe[1], URe[5]); dI = pk_sub(UIm[1], UIm[5]);
            ARe[5] = pk_mul_s(pk_add(dR, dI), C2);
            AIm[5] = pk_mul_s(pk_sub(dI, dR), C2);
            dR = pk_sub(URe[2], URe[6]); dI = pk_sub(UIm[2], UIm[6]);
            ARe[6] = dI;                         AIm[6] = pk_mul_s(dR, -1.f);
            dR = pk_sub(URe[3], URe[7]); dI = pk_sub(UIm[3], UIm[7]);
            ARe[7] = pk_mul_s(pk_sub(dI, dR), C2);
            AIm[7] = pk_mul_s(pk_add(dR, dI), -C2);
        }
        v2f BRe[8], BIm[8];
        #pragma unroll
        for (int g = 0; g < 8; g += 4) {
            BRe[g + 0] = pk_add(ARe[g + 0], ARe[g + 2]);  BIm[g + 0] = pk_add(AIm[g + 0], AIm[g + 2]);
            BRe[g + 1] = pk_add(ARe[g + 1], ARe[g + 3]);  BIm[g + 1] = pk_add(AIm[g + 1], AIm[g + 3]);
            BRe[g + 2] = pk_sub(ARe[g + 0], ARe[g + 2]);  BIm[g + 2] = pk_sub(AIm[g + 0], AIm[g + 2]);
            const v2f dR = pk_sub(ARe[g + 1], ARe[g + 3]);
            const v2f dI = pk_sub(AIm[g + 1], AIm[g + 3]);
            BRe[g + 3] = dI;  BIm[g + 3] = pk_mul_s(dR, -1.f);   // * (-i)
        }
        const int kmap[8] = { 0, 4, 2, 6, 1, 5, 3, 7 };   // DIF bitrev3
        #pragma unroll
        for (int p = 0; p < 8; ++p) {
            const int pb = p & ~1;
            v2f oR, oI;
            if (p & 1) { oR = pk_sub(BRe[pb], BRe[pb + 1]); oI = pk_sub(BIm[pb], BIm[pb + 1]); }
            else       { oR = pk_add(BRe[pb], BRe[pb + 1]); oI = pk_add(BIm[pb], BIm[pb + 1]); }
            const int mj = m + 4 * kmap[p];
            sxh[wave][0][c][mj] = pk_f16(oR.x, oI.x);   // signal x: (re, im)
            sxh[wave][1][c][mj] = pk_f16(oR.y, oI.y);   // signal y
        }
    }
    __syncthreads();

    // ---- Stage 2: lane (m2, sig) -> 7 bins via 16-pt radix-4 DFT
    const int blo = band_lo[NUMBAND];
    const int base = blo & ~31;
    float* px = frf[wave];        // alias: frf dead after stage 1; 224 slots
    float* py = frf[wave] + 224;
    {
        const int m2 = tid & 31;
        const int sig = tid >> 5;
        const float ang = -0.012271846303085130f * (float)(base + m2);  // -2pi k/512
        const v2f cksk = { __cosf(ang), __sinf(ang) };
        v2f cs = { 1.f, 0.f };
        v2f V[16];
        #pragma unroll
        for (int t0 = 0; t0 < 16; ++t0) {
            const v2f s = unpk_f16(sxh[wave][sig][t0][m2]);
            V[t0] = (t0 == 0) ? s : pk_cmul(cs, s);
            pk_rot(cs, cksk);
        }
        v2f G[4][4];
        #pragma unroll
        for (int rr = 0; rr < 4; ++rr) {
            const v2f A = pk_add(V[rr], V[rr + 8]);
            const v2f B = pk_sub(V[rr], V[rr + 8]);
            const v2f C = pk_add(V[rr + 4], V[rr + 12]);
            const v2f D = pk_sub(V[rr + 4], V[rr + 12]);
            G[0][rr] = pk_add(A, C);
            G[2][rr] = pk_sub(A, C);
            G[1][rr] = pk_bmi(B, D);
            G[3][rr] = pk_bpi(B, D);
        }
        float* pout = sig ? py : px;
        #define C1 0.92387953251f
        #define S1 0.38268343236f
        #define C2c 0.70710678119f
        // P = 0: plain sum
        {
            const v2f a_ = pk_add(pk_add(G[0][0], G[0][1]), pk_add(G[0][2], G[0][3]));
            pout[0 * 32 + m2] = fmaf(a_.x, a_.x, a_.y * a_.y);
        }
        #define XOUT(P, D, W1R, W1I, W2R, W2I, W3R, W3I) { \
            v2f a_ = G[D][0]; \
            pk_cfma(a_, G[D][1], W1R, W1I); \
            pk_cfma(a_, G[D][2], W2R, W2I); \
            pk_cfma(a_, G[D][3], W3R, W3I); \
            pout[(P) * 32 + m2] = fmaf(a_.x, a_.x, a_.y * a_.y); }
        XOUT(1, 1,  C1, -S1,     C2c, -C2c,   S1, -C1)
        XOUT(2, 2,  C2c, -C2c,   0.f, -1.f,  -C2c, -C2c)
        XOUT(3, 3,  S1, -C1,    -C2c, -C2c,  -C1,  S1)
        // P = 4: (G0 - G2) + (-i)(G1 - G3)
        {
            const v2f t1_ = pk_sub(G[0][0], G[0][2]);
            const v2f t2_ = pk_sub(G[0][1], G[0][3]);
            const v2f a_ = pk_bmi(t1_, t2_);
            pout[4 * 32 + m2] = fmaf(a_.x, a_.x, a_.y * a_.y);
        }
        XOUT(5, 1, -S1, -C1,    -C2c,  C2c,   C1,  S1)
        XOUT(6, 2, -C2c, -C2c,   0.f,  1.f,   C2c, -C2c)
        #undef XOUT
    }
    __syncthreads();

    // ---- Third-octave band sums: 4 lanes per band, both signals
    if (tid < 4 * NUMBAND && valid) {
        const int band = tid >> 2, s = tid & 3;
        const int lop = band_lo[band] - base, hip = band_hi[band] - base;
        const int u0 = lop >> 1, ul = (hip - 1) >> 1;
        float sx = 0.f, sy = 0.f;
        for (int u = u0 + s; u <= ul; u += 4) {
            const v2f pvx = *(const v2f*)&px[2 * u];
            const v2f pvy = *(const v2f*)&py[2 * u];
            const float m0 = (2 * u >= lop) ? 1.f : 0.f;
            const float m1 = (2 * u + 1 < hip) ? 1.f : 0.f;
            sx = fmaf(m0, pvx.x, sx); sx = fmaf(m1, pvx.y, sx);
            sy = fmaf(m0, pvy.x, sy); sy = fmaf(m1, pvy.y, sy);
        }
        sx += __shfl_xor(sx, 1, 64);  sx += __shfl_xor(sx, 2, 64);
        sy += __shfl_xor(sy, 1, 64);  sy += __shfl_xor(sy, 2, 64);
        if (s == 0) {
            xtob[((size_t)b * NUMBAND + band) * NSTFT + j] = sqrtf(sx + EPSF);
            ytob[((size_t)b * NUMBAND + band) * NSTFT + j] = sqrtf(sy + EPSF);
        }
    }
}

__global__ __launch_bounds__(256)
void k3_corr(const float* __restrict__ xtob, const float* __restrict__ ytob,
             const int* __restrict__ counts, float* __restrict__ out_)
{
    const int bb = blockIdx.y;
    const int b = bb / NUMBAND;
    const int band = bb % NUMBAND;
    const int s_base = blockIdx.x * 256;
    const int tid = threadIdx.x;
    const int seg = s_base + tid;

    __shared__ v2f lxy[256 + N_INTEL - 1];
    const float* xr = xtob + ((size_t)b * NUMBAND + band) * NSTFT;
    const float* yr = ytob + ((size_t)b * NUMBAND + band) * NSTFT;
    for (int i = tid; i < 256 + N_INTEL - 1; i += 256) {
        const int g = s_base + i;
        v2f v = { 0.f, 0.f };
        if (g < NSTFT) v = (v2f){ xr[g], yr[g] };
        lxy[i] = v;
    }
    __syncthreads();

    int nvalid = counts[b] - N_INTEL;
    if (nvalid < 0) nvalid = 0;
    if (nvalid > NSEG) nvalid = NSEG;

    float d = 0.f;
    if (seg < nvalid) {
        float xv[N_INTEL], yv[N_INTEL];
        float sx2 = 0.f, sy2 = 0.f;
        #pragma unroll
        for (int i = 0; i < N_INTEL; ++i) {
            const v2f v = lxy[tid + i];
            xv[i] = v.x; yv[i] = v.y;
            sx2 = fmaf(xv[i], xv[i], sx2);
            sy2 = fmaf(yv[i], yv[i], sy2);
        }
        const float nc = sqrtf(sx2) / (sqrtf(sy2) + EPSF);
        float sy = 0.f, sx = 0.f;
        #pragma unroll
        for (int i = 0; i < N_INTEL; ++i) {
            const float yp = fminf(yv[i] * nc, xv[i] * (1.f + CLIP_VAL));
            yv[i] = yp;
            sy += yp; sx += xv[i];
        }
        const float my = sy * (1.f / N_INTEL);
        const float mxm = sx * (1.f / N_INTEL);
        float num = 0.f, dy = 0.f, dx2 = 0.f;
        #pragma unroll
        for (int i = 0; i < N_INTEL; ++i) {
            const float a = yv[i] - my;
            const float c = xv[i] - mxm;
            num = fmaf(a, c, num);
            dy  = fmaf(a, a, dy);
            dx2 = fmaf(c, c, dx2);
        }
        d = num / ((sqrtf(dy) + EPSF) * (sqrtf(dx2) + EPSF));
    }

    #pragma unroll
    for (int o = 32; o > 0; o >>= 1) d += __shfl_down(d, o, 64);
    __shared__ float wsum[4];
    const int lane = threadIdx.x & 63, wid = threadIdx.x >> 6;
    if (lane == 0) wsum[wid] = d;
    __syncthreads();
    if (threadIdx.x == 0) {
        const float scale = -1.f / ((float)NUMBAND * ((float)nvalid + EPSF));
        atomicAdd(&out_[b], (wsum[0] + wsum[1] + wsum[2] + wsum[3]) * scale);
    }
}

extern "C" void kernel_launch(void* const* d_in, const int* in_sizes, int n_in,
                              void* d_out, int out_size, void* d_ws, size_t ws_size,
                              hipStream_t stream) {
    (void)in_sizes; (void)n_in; (void)out_size; (void)ws_size;
    const float* est = (const float*)d_in[0];
    const float* tgt = (const float*)d_in[1];
    const float* win = (const float*)d_in[2];
    const float* obm = (const float*)d_in[3];
    float* out = (float*)d_out;

    char* ws = (char*)d_ws;
    int*   counts  = (int*)(ws + WS_COUNTS);
    int*   band_lo = (int*)(ws + WS_BANDLO);
    int*   band_hi = (int*)(ws + WS_BANDHI);
    int*   srcfrm  = (int*)(ws + WS_SRCFRM);
    float* xtob    = (float*)(ws + WS_XTOB);
    float* ytob    = (float*)(ws + WS_YTOB);
    float2* ab     = (float2*)xtob;  // scratch alias: consumed by k1b before k2 writes

    k1a_ab<<<dim3(NB, 10), dim3(256), 0, stream>>>(tgt, win, obm, ab,
                                                   band_lo, band_hi, out);
    k1b_scan<<<dim3(NB), dim3(256), 0, stream>>>(ab, counts, srcfrm);
    k2_stft_tob<<<dim3(NWX, NB), dim3(128), 0, stream>>>(est, tgt, win, counts, srcfrm,
                                                         band_lo, band_hi, xtob, ytob);
    k3_corr<<<dim3((NSEG + 255) / 256, NB * NUMBAND), dim3(256), 0, stream>>>(xtob, ytob,
                                                                              counts, out);
}